// Round 18
// baseline (3732.978 us; speedup 1.0000x reference)
//
#include <hip/hip_runtime.h>

#define NN 100000
#define EE 400000
#define GG 4000
#define EMB 300
#define EMB2 600
#define LL 5
#define BN_EPS 1e-5f
#define BUF_BYTES 120000000ull

typedef __attribute__((ext_vector_type(8))) short bf16x8;
typedef __attribute__((ext_vector_type(4))) float f32x4;

__device__ __constant__ int c_atom_off[9] = {0,119,123,135,147,157,163,169,171};

static __device__ __forceinline__ float u16tof(unsigned short u) {
    return __uint_as_float(((unsigned int)u) << 16);
}
// f32 -> bf16 bits, round-to-nearest-even
static __device__ __forceinline__ unsigned short ftobf(float f) {
    unsigned int u = __float_as_uint(f);
    unsigned int r = 0x7fffu + ((u >> 16) & 1u);
    return (unsigned short)((u + r) >> 16);
}
static __device__ __forceinline__ int geti(const void* p, int f64, long long i) {
    return f64 ? (int)((const long long*)p)[i] : ((const int*)p)[i];
}
// split floats into bf16 hi + bf16 lo (lo = rnd(x - hi))
static __device__ __forceinline__ void split8(const float* vv, bf16x8& hi, bf16x8& lo) {
#pragma unroll
    for (int e = 0; e < 8; ++e) {
        const unsigned short h = ftobf(vv[e]);
        hi[e] = (short)h;
        lo[e] = (short)ftobf(vv[e] - u16tof(h));
    }
}
static __device__ __forceinline__ f32x4 mfma16(bf16x8 a, bf16x8 b, f32x4 c) {
    return __builtin_amdgcn_mfma_f32_16x16x32_bf16(a, b, c, 0, 0, 0);
}

__global__ void k_detect(const int* __restrict__ ei, int* __restrict__ flag) {
    __shared__ int cnt;
    if (threadIdx.x == 0) cnt = 0;
    __syncthreads();
    int z = 0;
    for (int i = threadIdx.x; i < 1024; i += 256)
        if (ei[2 * i + 1] == 0) z++;
    atomicAdd(&cnt, z);
    __syncthreads();
    if (threadIdx.x == 0) *flag = (cnt > 512) ? 1 : 0;
}

__global__ void k_init(float* __restrict__ sc2, float* __restrict__ sh2) {
    const int c = blockIdx.x * 256 + threadIdx.x;
    if (c < EMB) { sc2[c] = 1.f; sh2[c] = 0.f; }
}

__global__ void k_encode(const void* __restrict__ x, const float* __restrict__ aemb,
                         float* __restrict__ h, const int* __restrict__ flag) {
    __shared__ int xi[4][9];
    const int ty = threadIdx.y, tx = threadIdx.x;
    const int n = blockIdx.x * 4 + ty;
    const int f64 = *flag;
    if (tx < 9) xi[ty][tx] = geti(x, f64, (long long)n * 9 + tx) + c_atom_off[tx];
    __syncthreads();
    if (tx < 75) {
        const int c = tx * 4;
        float s0 = 0.f, s1 = 0.f, s2 = 0.f, s3 = 0.f;
#pragma unroll
        for (int f = 0; f < 9; ++f) {
            const float4 v = *(const float4*)(aemb + (size_t)xi[ty][f] * EMB + c);
            s0 += v.x; s1 += v.y; s2 += v.z; s3 += v.w;
        }
        float4 o; o.x = s0; o.y = s1; o.z = s2; o.w = s3;
        *(float4*)(h + (size_t)n * EMB + c) = o;
    }
}

// ---------------- CSR build ----------------
__global__ void k_deg(const void* __restrict__ ei, int* __restrict__ deg,
                      const int* __restrict__ flag) {
    const int e = blockIdx.x * 256 + threadIdx.x;
    if (e < EE) atomicAdd(&deg[geti(ei, *flag, (long long)EE + e)], 1);
}

__global__ __launch_bounds__(1024) void k_scan(const int* __restrict__ deg,
                                               int* __restrict__ rowstart,
                                               int* __restrict__ cursor) {
    __shared__ int part[1024];
    const int t = threadIdx.x;
    const int c0 = t * 98;
    const int c1 = (c0 + 98 < NN) ? c0 + 98 : NN;
    int s = 0;
    for (int i = c0; i < c1; ++i) s += deg[i];
    part[t] = s;
    __syncthreads();
    for (int off = 1; off < 1024; off <<= 1) {
        int v = (t >= off) ? part[t - off] : 0;
        __syncthreads();
        part[t] += v;
        __syncthreads();
    }
    int run = part[t] - s;
    for (int i = c0; i < c1; ++i) {
        rowstart[i] = run; cursor[i] = run;
        run += deg[i];
    }
    if (c1 == NN && c0 <= NN) rowstart[NN] = run;
}

__global__ void k_scatter(const void* __restrict__ ei, const void* __restrict__ eattr,
                          int* __restrict__ cursor, int* __restrict__ elist,
                          const int* __restrict__ flag) {
    const int e = blockIdx.x * 256 + threadIdx.x;
    if (e >= EE) return;
    const int f64 = *flag;
    const int src = geti(ei, f64, e);
    const int dst = geti(ei, f64, (long long)EE + e);
    const int b0 = geti(eattr, f64, (long long)e * 3 + 0);
    const int b1 = geti(eattr, f64, (long long)e * 3 + 1);
    const int b2 = geti(eattr, f64, (long long)e * 3 + 2);
    const int pos = atomicAdd(&cursor[dst], 1);
    elist[pos] = src * 64 + b0 * 12 + b1 * 2 + b2;
}

__global__ void k_ebc(const float* __restrict__ bemb, float* __restrict__ ebc) {
    const int cb = blockIdx.x;
    const int tx = threadIdx.x;
    if (tx >= 75) return;
    const int b0 = cb / 12, b1 = (cb / 2) % 6, b2 = cb & 1;
    const int c = tx * 4;
    const float4 v0 = *(const float4*)(bemb + (size_t)b0 * EMB + c);
    const float4 v1 = *(const float4*)(bemb + (size_t)(5 + b1) * EMB + c);
    const float4 v2 = *(const float4*)(bemb + (size_t)(11 + b2) * EMB + c);
    float4 o; o.x = v0.x + v1.x + v2.x; o.y = v0.y + v1.y + v2.y;
    o.z = v0.z + v1.z + v2.z; o.w = v0.w + v1.w + v2.w;
    *(float4*)(ebc + (size_t)cb * EMB + c) = o;
}

// ---- edge-parallel gather: one node per block, ty = edge slot (4 concurrent chains) ----
// z[n] = h'(n) + sum_j relu(h'(src_j)+e_j), h' = dorelu ? relu(h*sc+sh) : h*sc+sh
__global__ void k_gather(const int* __restrict__ rowstart, const int* __restrict__ elist,
                         const float* __restrict__ ebc,
                         const float* __restrict__ h, float* __restrict__ z,
                         const float* __restrict__ sc, const float* __restrict__ sh,
                         int dorelu) {
    __shared__ float red[3][EMB];
    const int ty = threadIdx.y, tx = threadIdx.x;
    const int n = blockIdx.x;
    const int s = rowstart[n], e = rowstart[n + 1];
    float4 acc = {0.f, 0.f, 0.f, 0.f};
    if (tx < 75) {
        const int c = tx * 4;
        const float4 s4 = *(const float4*)(sc + c);
        const float4 h4 = *(const float4*)(sh + c);
        if (ty == 0) {   // self term
            float4 v = *(const float4*)(h + (size_t)n * EMB + c);
            v.x = fmaf(v.x, s4.x, h4.x); v.y = fmaf(v.y, s4.y, h4.y);
            v.z = fmaf(v.z, s4.z, h4.z); v.w = fmaf(v.w, s4.w, h4.w);
            if (dorelu) {
                v.x = fmaxf(v.x, 0.f); v.y = fmaxf(v.y, 0.f);
                v.z = fmaxf(v.z, 0.f); v.w = fmaxf(v.w, 0.f);
            }
            acc = v;
        }
        for (int j = s + ty; j < e; j += 4) {
            const int packed = elist[j];
            const int src = packed >> 6, cb = packed & 63;
            float4 hv = *(const float4*)(h + (size_t)src * EMB + c);
            const float4 ev = *(const float4*)(ebc + (size_t)cb * EMB + c);
            hv.x = fmaf(hv.x, s4.x, h4.x); hv.y = fmaf(hv.y, s4.y, h4.y);
            hv.z = fmaf(hv.z, s4.z, h4.z); hv.w = fmaf(hv.w, s4.w, h4.w);
            if (dorelu) {
                hv.x = fmaxf(hv.x, 0.f); hv.y = fmaxf(hv.y, 0.f);
                hv.z = fmaxf(hv.z, 0.f); hv.w = fmaxf(hv.w, 0.f);
            }
            acc.x += fmaxf(hv.x + ev.x, 0.f);
            acc.y += fmaxf(hv.y + ev.y, 0.f);
            acc.z += fmaxf(hv.z + ev.z, 0.f);
            acc.w += fmaxf(hv.w + ev.w, 0.f);
        }
        if (ty > 0) *(float4*)(&red[ty - 1][tx * 4]) = acc;
    }
    __syncthreads();
    if (ty == 0 && tx < 75) {
        const int c = tx * 4;
        acc.x += red[0][c + 0] + red[1][c + 0] + red[2][c + 0];
        acc.y += red[0][c + 1] + red[1][c + 1] + red[2][c + 1];
        acc.z += red[0][c + 2] + red[1][c + 2] + red[2][c + 2];
        acc.w += red[0][c + 3] + red[1][c + 3] + red[2][c + 3];
        *(float4*)(z + (size_t)n * EMB + c) = acc;
    }
}

// ---- W1 -> fragment-linear bf16 hi/lo: w[kt 0..9][nt 0..39][lane 0..63][8] ----
__global__ void k_wconv1(const float* __restrict__ W, unsigned short* __restrict__ hi,
                         unsigned short* __restrict__ lo) {
    const int idx = blockIdx.x * 256 + threadIdx.x;
    if (idx >= 10 * 40 * 64 * 8) return;
    const int e = idx & 7;
    const int lane = (idx >> 3) & 63;
    const int nt = (idx >> 9) % 40;
    const int kt = idx / 20480;
    const int r = lane & 15, g = lane >> 4;
    const int col = nt * 16 + r;
    const int k = kt * 32 + g * 8 + e;
    const float w = (col < EMB2 && k < EMB) ? W[(size_t)k * EMB2 + col] : 0.f;
    const unsigned short h = ftobf(w);
    hi[idx] = h;
    lo[idx] = ftobf(w - u16tof(h));
}
// ---- W2 -> fragment-linear: w[kt 0..18][nt 0..19][lane][8] ----
__global__ void k_wconv2(const float* __restrict__ W, unsigned short* __restrict__ hi,
                         unsigned short* __restrict__ lo) {
    const int idx = blockIdx.x * 256 + threadIdx.x;
    if (idx >= 19 * 20 * 64 * 8) return;
    const int e = idx & 7;
    const int lane = (idx >> 3) & 63;
    const int nt = (idx >> 9) % 20;
    const int kt = idx / 10240;
    const int r = lane & 15, g = lane >> 4;
    const int col = nt * 16 + r;
    const int k = kt * 32 + g * 8 + e;
    const float w = (col < EMB && k < EMB2) ? W[(size_t)k * EMB + col] : 0.f;
    const unsigned short h = ftobf(w);
    hi[idx] = h;
    lo[idx] = ftobf(w - u16tof(h));
}

// ---- MFMA GEMM1: 32-row blocks (grid 3125), 512 thr, 8 waves x 5 nt x 2 rowgroups ----
// z1a (cols<300) -> Q in-place (barrier-protected), z1b (300-599) -> P. dbuf pipeline.
__global__ __launch_bounds__(512) void k_mfma1(
    float* __restrict__ P, float* Q,
    const unsigned short* __restrict__ whi, const unsigned short* __restrict__ wlo)
{
    __shared__ __align__(16) short AsH[2][1024];   // [buf][rg 0..1][lane][8]
    __shared__ __align__(16) short AsL[2][1024];
    const int tid = threadIdx.x;
    const int lane = tid & 63;
    const int wn = tid >> 6;                    // 0..7
    const int g = lane >> 4, r = lane & 15;
    const int row0 = blockIdx.x * 32;
    const int srl = tid & 31, stg = tid >> 5;
    const int srow = row0 + srl;
    const int sldo = (srl >> 4) * 512 + (stg * 16 + (srl & 15)) * 8;
    f32x4 acc[2][5];
#pragma unroll
    for (int rg = 0; rg < 2; ++rg)
#pragma unroll
        for (int t = 0; t < 5; ++t) acc[rg][t] = (f32x4){0.f, 0.f, 0.f, 0.f};

    // prologue: stage kt=0 into buf 0
    if (tid < 128) {
        float vv[8];
#pragma unroll
        for (int hh = 0; hh < 2; ++hh) {
            const int cc = stg * 8 + hh * 4;
            float4 v = {0.f, 0.f, 0.f, 0.f};
            if (cc + 3 < EMB) v = *(const float4*)(Q + (size_t)srow * EMB + cc);
            vv[hh * 4 + 0] = v.x; vv[hh * 4 + 1] = v.y;
            vv[hh * 4 + 2] = v.z; vv[hh * 4 + 3] = v.w;
        }
        bf16x8 hi8, lo8;
        split8(vv, hi8, lo8);
        *(bf16x8*)(&AsH[0][sldo]) = hi8;
        *(bf16x8*)(&AsL[0][sldo]) = lo8;
    }
    __syncthreads();

    for (int kt = 0; kt < 10; ++kt) {
        const int cur = kt & 1;
        float vv[8];
        const bool have = (kt + 1 < 10) && (tid < 128);
        if (have) {
            const int kb0 = (kt + 1) * 32;
#pragma unroll
            for (int hh = 0; hh < 2; ++hh) {
                const int cc = kb0 + stg * 8 + hh * 4;
                float4 v = {0.f, 0.f, 0.f, 0.f};
                if (cc + 3 < EMB) v = *(const float4*)(Q + (size_t)srow * EMB + cc);
                vv[hh * 4 + 0] = v.x; vv[hh * 4 + 1] = v.y;
                vv[hh * 4 + 2] = v.z; vv[hh * 4 + 3] = v.w;
            }
        }
        bf16x8 ah[2], al[2];
#pragma unroll
        for (int rg = 0; rg < 2; ++rg) {
            ah[rg] = *(const bf16x8*)(&AsH[cur][rg * 512 + lane * 8]);
            al[rg] = *(const bf16x8*)(&AsL[cur][rg * 512 + lane * 8]);
        }
#pragma unroll
        for (int t = 0; t < 5; ++t) {
            const size_t wb = ((size_t)(kt * 40 + wn + t * 8) * 64 + lane) * 8;
            const bf16x8 bh = *(const bf16x8*)(whi + wb);
            const bf16x8 bl = *(const bf16x8*)(wlo + wb);
#pragma unroll
            for (int rg = 0; rg < 2; ++rg) {
                acc[rg][t] = mfma16(al[rg], bh, acc[rg][t]);
                acc[rg][t] = mfma16(ah[rg], bl, acc[rg][t]);
                acc[rg][t] = mfma16(ah[rg], bh, acc[rg][t]);
            }
        }
        if (have) {
            bf16x8 hi8, lo8;
            split8(vv, hi8, lo8);
            *(bf16x8*)(&AsH[cur ^ 1][sldo]) = hi8;
            *(bf16x8*)(&AsL[cur ^ 1][sldo]) = lo8;
        }
        __syncthreads();
    }
    // epilogue: all Q reads complete (barrier above)
#pragma unroll
    for (int t = 0; t < 5; ++t) {
        const int col = (wn + t * 8) * 16 + r;
#pragma unroll
        for (int rg = 0; rg < 2; ++rg) {
            const int orow = row0 + rg * 16 + g * 4;
#pragma unroll
            for (int j = 0; j < 4; ++j) {
                const float val = acc[rg][t][j];
                if (col < EMB)       Q[(size_t)(orow + j) * EMB + col] = val;          // z1a -> Q
                else if (col < EMB2) P[(size_t)(orow + j) * EMB + (col - EMB)] = val;  // z1b -> P
            }
        }
    }
}

// ---- MFMA GEMM2: 32-row blocks, 256 thr, 4 waves x 5 nt x 2 rowgroups; dbuf ----
__global__ __launch_bounds__(256) void k_mfma2(
    float* P, const float* __restrict__ Qa,
    const float* __restrict__ sc, const float* __restrict__ sh,
    const unsigned short* __restrict__ whi, const unsigned short* __restrict__ wlo)
{
    __shared__ __align__(16) short AsH[2][1024];
    __shared__ __align__(16) short AsL[2][1024];
    const int tid = threadIdx.x;
    const int lane = tid & 63;
    const int wn = tid >> 6;
    const int g = lane >> 4, r = lane & 15;
    const int row0 = blockIdx.x * 32;
    const int srl = tid & 31, stg = (tid >> 5) & 3;
    const int srow = row0 + srl;
    const int sldo = (srl >> 4) * 512 + (stg * 16 + (srl & 15)) * 8;
    f32x4 acc[2][5];
#pragma unroll
    for (int rg = 0; rg < 2; ++rg)
#pragma unroll
        for (int t = 0; t < 5; ++t) acc[rg][t] = (f32x4){0.f, 0.f, 0.f, 0.f};

    auto loadA = [&](int kt, float vv[8]) {
#pragma unroll
        for (int hh = 0; hh < 2; ++hh) {
            const int cc = kt * 32 + stg * 8 + hh * 4;
            float4 v = {0.f, 0.f, 0.f, 0.f};
            if (cc + 3 < EMB) {
                v = *(const float4*)(Qa + (size_t)srow * EMB + cc);
            } else if (cc >= EMB && cc + 3 < EMB2) {
                v = *(const float4*)(P + (size_t)srow * EMB + cc - EMB);
            } else if (cc < EMB2) {
#pragma unroll
                for (int e = 0; e < 4; ++e) {
                    const int k = cc + e;
                    ((float*)&v)[e] = (k < EMB) ? Qa[(size_t)srow * EMB + k]
                                    : (k < EMB2 ? P[(size_t)srow * EMB + (k - EMB)] : 0.f);
                }
            }
            vv[hh * 4 + 0] = v.x; vv[hh * 4 + 1] = v.y;
            vv[hh * 4 + 2] = v.z; vv[hh * 4 + 3] = v.w;
        }
    };
    auto writeA = [&](int kt, int b, float vv[8]) {
        float ww[8];
#pragma unroll
        for (int e = 0; e < 8; ++e) {
            const int k = kt * 32 + stg * 8 + e;
            float v = vv[e];
            if (k < EMB2) v = fmaxf(fmaf(v, sc[k], sh[k]), 0.f);
            else v = 0.f;
            ww[e] = v;
        }
        bf16x8 hi8, lo8;
        split8(ww, hi8, lo8);
        *(bf16x8*)(&AsH[b][sldo]) = hi8;
        *(bf16x8*)(&AsL[b][sldo]) = lo8;
    };

    if (tid < 128) {
        float vv[8];
        loadA(0, vv);
        writeA(0, 0, vv);
    }
    __syncthreads();

    for (int kt = 0; kt < 19; ++kt) {
        const int cur = kt & 1;
        float vv[8];
        const bool have = (kt + 1 < 19) && (tid < 128);
        if (have) loadA(kt + 1, vv);
        bf16x8 ah[2], al[2];
#pragma unroll
        for (int rg = 0; rg < 2; ++rg) {
            ah[rg] = *(const bf16x8*)(&AsH[cur][rg * 512 + lane * 8]);
            al[rg] = *(const bf16x8*)(&AsL[cur][rg * 512 + lane * 8]);
        }
#pragma unroll
        for (int t = 0; t < 5; ++t) {
            const size_t wb = ((size_t)(kt * 20 + wn + t * 4) * 64 + lane) * 8;
            const bf16x8 bh = *(const bf16x8*)(whi + wb);
            const bf16x8 bl = *(const bf16x8*)(wlo + wb);
#pragma unroll
            for (int rg = 0; rg < 2; ++rg) {
                acc[rg][t] = mfma16(al[rg], bh, acc[rg][t]);
                acc[rg][t] = mfma16(ah[rg], bl, acc[rg][t]);
                acc[rg][t] = mfma16(ah[rg], bh, acc[rg][t]);
            }
        }
        if (have) writeA(kt + 1, cur ^ 1, vv);
        __syncthreads();
    }
#pragma unroll
    for (int t = 0; t < 5; ++t) {
        const int col = (wn + t * 4) * 16 + r;
        if (col < EMB) {
#pragma unroll
            for (int rg = 0; rg < 2; ++rg) {
                const int orow = row0 + rg * 16 + g * 4;
#pragma unroll
                for (int j = 0; j < 4; ++j)
                    P[(size_t)(orow + j) * EMB + col] = acc[rg][t][j];
            }
        }
    }
}

__global__ void k_stats(const float* __restrict__ m, float* __restrict__ sum, float* __restrict__ ss) {
    const int c = blockIdx.x * 256 + threadIdx.x;
    if (c >= EMB) return;
    const int r0 = blockIdx.y * 200;
    const int r1 = r0 + 200;
    float s = 0.f, q = 0.f;
    for (int r = r0; r < r1; ++r) {
        const float v = m[(size_t)r * EMB + c];
        s += v; q += v * v;
    }
    atomicAdd(&sum[c], s);
    atomicAdd(&ss[c], q);
}

__global__ void k_scale(const float* __restrict__ sum, const float* __restrict__ ss,
                        const float* __restrict__ g, const float* __restrict__ b,
                        float* __restrict__ scale, float* __restrict__ shift, int C) {
    const int c = blockIdx.x * 256 + threadIdx.x;
    if (c >= C) return;
    const float invN = 1.0f / (float)NN;
    const float mean = sum[c] * invN;
    const float var = ss[c] * invN - mean * mean;
    const float s = g[c] * rsqrtf(var + BN_EPS);
    scale[c] = s;
    shift[c] = b[c] - mean * s;
}

// ---- pooling with fused BN2 (no relu, last layer) ----
__global__ void k_poolg(const void* __restrict__ batch, const float* __restrict__ h,
                        float* __restrict__ out, const int* __restrict__ flag,
                        const float* __restrict__ sc, const float* __restrict__ sh) {
    __shared__ float red[4][EMB];
    const int g = blockIdx.x;
    const int f64 = *flag;
    int lo = 0, hi = NN;
    while (lo < hi) { int mid = (lo + hi) >> 1; if (geti(batch, f64, mid) < g) lo = mid + 1; else hi = mid; }
    const int s = lo;
    hi = NN;
    while (lo < hi) { int mid = (lo + hi) >> 1; if (geti(batch, f64, mid) < g + 1) lo = mid + 1; else hi = mid; }
    const int e = lo;
    const int tx = threadIdx.x, ty = threadIdx.y;
    if (tx < 75) {
        const int c = tx * 4;
        const float4 s4 = *(const float4*)(sc + c);
        const float4 h4 = *(const float4*)(sh + c);
        float4 acc; acc.x = acc.y = acc.z = acc.w = 0.f;
        int cntr = 0;
        for (int r = s + ty; r < e; r += 4) {
            const float4 v = *(const float4*)(h + (size_t)r * EMB + c);
            acc.x += v.x; acc.y += v.y; acc.z += v.z; acc.w += v.w;
            cntr++;
        }
        acc.x = fmaf(acc.x, s4.x, cntr * h4.x);
        acc.y = fmaf(acc.y, s4.y, cntr * h4.y);
        acc.z = fmaf(acc.z, s4.z, cntr * h4.z);
        acc.w = fmaf(acc.w, s4.w, cntr * h4.w);
        *(float4*)(&red[ty][c]) = acc;
    }
    __syncthreads();
    if (ty == 0 && tx < 75) {
        const int c = tx * 4;
        float4 o;
        o.x = red[0][c + 0] + red[1][c + 0] + red[2][c + 0] + red[3][c + 0];
        o.y = red[0][c + 1] + red[1][c + 1] + red[2][c + 1] + red[3][c + 1];
        o.z = red[0][c + 2] + red[1][c + 2] + red[2][c + 2] + red[3][c + 2];
        o.w = red[0][c + 3] + red[1][c + 3] + red[2][c + 3] + red[3][c + 3];
        *(float4*)(out + (size_t)g * EMB + c) = o;
    }
}

extern "C" void kernel_launch(void* const* d_in, const int* in_sizes, int n_in,
                              void* d_out, int out_size, void* d_ws, size_t ws_size,
                              hipStream_t stream) {
    const void* x     = d_in[0];
    const void* ei    = d_in[1];
    const void* eattr = d_in[2];
    const void* batch = d_in[3];
    const float* aemb = (const float*)d_in[4];
    const float* bemb = (const float*)d_in[5];
    const float* W1   = (const float*)d_in[6];
    const float* g1   = (const float*)d_in[8];
    const float* bt1  = (const float*)d_in[9];
    const float* W2   = (const float*)d_in[10];
    const float* g2   = (const float*)d_in[12];
    const float* bt2  = (const float*)d_in[13];

    char* ws = (char*)d_ws;
    float* P  = (float*)(ws);
    float* Q  = (float*)(ws + BUF_BYTES);
    char*  aux = ws + 2 * BUF_BYTES;
    float* st = (float*)(aux);
    float* sum1 = st;         float* ss1 = st + 600;
    float* sum2 = st + 1200;  float* ss2 = st + 1500;
    float* sc1  = st + 1800;  float* sh1 = st + 2400;
    float* sc2  = st + 3000;  float* sh2 = st + 3300;
    int* flag     = (int*)(aux + 16384);
    int* deg      = (int*)(aux + 16384 + 64);
    int* rowstart = (int*)(aux + 16384 + 64 + 400064);
    int* cursor   = (int*)(aux + 16384 + 64 + 800128);
    int* elist    = (int*)(aux + 16384 + 64 + 1200192);
    float* ebc    = (float*)(aux + 16384 + 64 + 2800192);
    unsigned short* wt1hi = (unsigned short*)(aux + 2888640);
    unsigned short* wt1lo = (unsigned short*)(aux + 2888640 + 409600);
    unsigned short* wt2hi = (unsigned short*)(aux + 2888640 + 819200);
    unsigned short* wt2lo = (unsigned short*)(aux + 2888640 + 819200 + 389120);

    const dim3 blk80x4(80, 4);

    k_detect<<<1, 256, 0, stream>>>((const int*)ei, flag);
    k_init<<<2, 256, 0, stream>>>(sc2, sh2);

    (void)hipMemsetAsync(deg, 0, NN * sizeof(int), stream);
    k_deg<<<(EE + 255) / 256, 256, 0, stream>>>(ei, deg, flag);
    k_scan<<<1, 1024, 0, stream>>>(deg, rowstart, cursor);
    k_scatter<<<(EE + 255) / 256, 256, 0, stream>>>(ei, eattr, cursor, elist, flag);
    k_ebc<<<60, 80, 0, stream>>>(bemb, ebc);

    k_encode<<<NN / 4, blk80x4, 0, stream>>>(x, aemb, P, flag);

    for (int i = 0; i < LL; ++i) {
        const float* W1i = W1 + (size_t)i * EMB * EMB2;
        const float* W2i = W2 + (size_t)i * EMB2 * EMB;

        (void)hipMemsetAsync(st, 0, 1800 * sizeof(float), stream);
        k_wconv1<<<(204800 + 255) / 256, 256, 0, stream>>>(W1i, wt1hi, wt1lo);
        k_wconv2<<<(194560 + 255) / 256, 256, 0, stream>>>(W2i, wt2hi, wt2lo);

        // z (in Q) = h' + sum relu(h'+e)  — edge-parallel, one node per block
        k_gather<<<NN, blk80x4, 0, stream>>>(rowstart, elist, ebc, P, Q,
                                             sc2, sh2, (i > 0) ? 1 : 0);

        // z1 = z @ W1 (32-row blocks): z1a -> Q in-place, z1b -> P
        k_mfma1<<<NN / 32, 512, 0, stream>>>(P, Q, wt1hi, wt1lo);

        k_stats<<<dim3(2, 500), 256, 0, stream>>>(Q, sum1, ss1);
        k_stats<<<dim3(2, 500), 256, 0, stream>>>(P, sum1 + EMB, ss1 + EMB);
        k_scale<<<3, 256, 0, stream>>>(sum1, ss1, g1 + (size_t)i * EMB2, bt1 + (size_t)i * EMB2,
                                       sc1, sh1, EMB2);

        // h_pre = relu(BN1([Q|P])) @ W2 -> P in-place (32-row blocks)
        k_mfma2<<<NN / 32, 256, 0, stream>>>(P, Q, sc1, sh1, wt2hi, wt2lo);

        k_stats<<<dim3(2, 500), 256, 0, stream>>>(P, sum2, ss2);
        k_scale<<<2, 256, 0, stream>>>(sum2, ss2, g2 + (size_t)i * EMB, bt2 + (size_t)i * EMB,
                                       sc2, sh2, EMB);
    }

    k_poolg<<<GG, blk80x4, 0, stream>>>(batch, P, (float*)d_out, flag, sc2, sh2);
}

// Round 19
// 3438.274 us; speedup vs baseline: 1.0857x; 1.0857x over previous
//
#include <hip/hip_runtime.h>

#define NN 100000
#define EE 400000
#define GG 4000
#define EMB 300
#define EMB2 600
#define LL 5
#define BN_EPS 1e-5f
#define BUF_BYTES 120000000ull

typedef __attribute__((ext_vector_type(8))) short bf16x8;
typedef __attribute__((ext_vector_type(4))) short bf16x4;
typedef __attribute__((ext_vector_type(2))) short bf16x2;
typedef __attribute__((ext_vector_type(4))) float f32x4;

__device__ __constant__ int c_atom_off[9] = {0,119,123,135,147,157,163,169,171};

static __device__ __forceinline__ float u16tof(unsigned short u) {
    return __uint_as_float(((unsigned int)u) << 16);
}
// f32 -> bf16 bits, round-to-nearest-even
static __device__ __forceinline__ unsigned short ftobf(float f) {
    unsigned int u = __float_as_uint(f);
    unsigned int r = 0x7fffu + ((u >> 16) & 1u);
    return (unsigned short)((u + r) >> 16);
}
static __device__ __forceinline__ int geti(const void* p, int f64, long long i) {
    return f64 ? (int)((const long long*)p)[i] : ((const int*)p)[i];
}
static __device__ __forceinline__ f32x4 mfma16(bf16x8 a, bf16x8 b, f32x4 c) {
    return __builtin_amdgcn_mfma_f32_16x16x32_bf16(a, b, c, 0, 0, 0);
}

__global__ void k_detect(const int* __restrict__ ei, int* __restrict__ flag) {
    __shared__ int cnt;
    if (threadIdx.x == 0) cnt = 0;
    __syncthreads();
    int z = 0;
    for (int i = threadIdx.x; i < 1024; i += 256)
        if (ei[2 * i + 1] == 0) z++;
    atomicAdd(&cnt, z);
    __syncthreads();
    if (threadIdx.x == 0) *flag = (cnt > 512) ? 1 : 0;
}

__global__ void k_init(float* __restrict__ sc2, float* __restrict__ sh2) {
    const int c = blockIdx.x * 256 + threadIdx.x;
    if (c < EMB) { sc2[c] = 1.f; sh2[c] = 0.f; }
}

__global__ void k_encode(const void* __restrict__ x, const float* __restrict__ aemb,
                         float* __restrict__ h, const int* __restrict__ flag) {
    __shared__ int xi[4][9];
    const int ty = threadIdx.y, tx = threadIdx.x;
    const int n = blockIdx.x * 4 + ty;
    const int f64 = *flag;
    if (tx < 9) xi[ty][tx] = geti(x, f64, (long long)n * 9 + tx) + c_atom_off[tx];
    __syncthreads();
    if (tx < 75) {
        const int c = tx * 4;
        float s0 = 0.f, s1 = 0.f, s2 = 0.f, s3 = 0.f;
#pragma unroll
        for (int f = 0; f < 9; ++f) {
            const float4 v = *(const float4*)(aemb + (size_t)xi[ty][f] * EMB + c);
            s0 += v.x; s1 += v.y; s2 += v.z; s3 += v.w;
        }
        float4 o; o.x = s0; o.y = s1; o.z = s2; o.w = s3;
        *(float4*)(h + (size_t)n * EMB + c) = o;
    }
}

// ---------------- CSR build ----------------
__global__ void k_deg(const void* __restrict__ ei, int* __restrict__ deg,
                      const int* __restrict__ flag) {
    const int e = blockIdx.x * 256 + threadIdx.x;
    if (e < EE) atomicAdd(&deg[geti(ei, *flag, (long long)EE + e)], 1);
}

__global__ __launch_bounds__(1024) void k_scan(const int* __restrict__ deg,
                                               int* __restrict__ rowstart,
                                               int* __restrict__ cursor) {
    __shared__ int part[1024];
    const int t = threadIdx.x;
    const int c0 = t * 98;
    const int c1 = (c0 + 98 < NN) ? c0 + 98 : NN;
    int s = 0;
    for (int i = c0; i < c1; ++i) s += deg[i];
    part[t] = s;
    __syncthreads();
    for (int off = 1; off < 1024; off <<= 1) {
        int v = (t >= off) ? part[t - off] : 0;
        __syncthreads();
        part[t] += v;
        __syncthreads();
    }
    int run = part[t] - s;
    for (int i = c0; i < c1; ++i) {
        rowstart[i] = run; cursor[i] = run;
        run += deg[i];
    }
    if (c1 == NN && c0 <= NN) rowstart[NN] = run;
}

__global__ void k_scatter(const void* __restrict__ ei, const void* __restrict__ eattr,
                          int* __restrict__ cursor, int* __restrict__ elist,
                          const int* __restrict__ flag) {
    const int e = blockIdx.x * 256 + threadIdx.x;
    if (e >= EE) return;
    const int f64 = *flag;
    const int src = geti(ei, f64, e);
    const int dst = geti(ei, f64, (long long)EE + e);
    const int b0 = geti(eattr, f64, (long long)e * 3 + 0);
    const int b1 = geti(eattr, f64, (long long)e * 3 + 1);
    const int b2 = geti(eattr, f64, (long long)e * 3 + 2);
    const int pos = atomicAdd(&cursor[dst], 1);
    elist[pos] = src * 64 + b0 * 12 + b1 * 2 + b2;
}

__global__ void k_ebc(const float* __restrict__ bemb, float* __restrict__ ebc) {
    const int cb = blockIdx.x;
    const int tx = threadIdx.x;
    if (tx >= 75) return;
    const int b0 = cb / 12, b1 = (cb / 2) % 6, b2 = cb & 1;
    const int c = tx * 4;
    const float4 v0 = *(const float4*)(bemb + (size_t)b0 * EMB + c);
    const float4 v1 = *(const float4*)(bemb + (size_t)(5 + b1) * EMB + c);
    const float4 v2 = *(const float4*)(bemb + (size_t)(11 + b2) * EMB + c);
    float4 o; o.x = v0.x + v1.x + v2.x; o.y = v0.y + v1.y + v2.y;
    o.z = v0.z + v1.z + v2.z; o.w = v0.w + v1.w + v2.w;
    *(float4*)(ebc + (size_t)cb * EMB + c) = o;
}

// ---- gather (R17 form): 4 nodes/block, serial edge walk, fused BN2+relu ----
__global__ void k_gather(const int* __restrict__ rowstart, const int* __restrict__ elist,
                         const float* __restrict__ ebc,
                         const float* __restrict__ h, float* __restrict__ z,
                         const float* __restrict__ sc, const float* __restrict__ sh,
                         int dorelu) {
    const int ty = threadIdx.y, tx = threadIdx.x;
    const int n = blockIdx.x * 4 + ty;
    if (tx >= 75) return;
    const int c = tx * 4;
    const float4 s4 = *(const float4*)(sc + c);
    const float4 h4 = *(const float4*)(sh + c);
    const int s = rowstart[n], e = rowstart[n + 1];
    float4 acc;
    {
        float4 v = *(const float4*)(h + (size_t)n * EMB + c);
        v.x = fmaf(v.x, s4.x, h4.x); v.y = fmaf(v.y, s4.y, h4.y);
        v.z = fmaf(v.z, s4.z, h4.z); v.w = fmaf(v.w, s4.w, h4.w);
        if (dorelu) {
            v.x = fmaxf(v.x, 0.f); v.y = fmaxf(v.y, 0.f);
            v.z = fmaxf(v.z, 0.f); v.w = fmaxf(v.w, 0.f);
        }
        acc = v;
    }
    for (int j = s; j < e; ++j) {
        const int packed = elist[j];
        const int src = packed >> 6, cb = packed & 63;
        float4 hv = *(const float4*)(h + (size_t)src * EMB + c);
        const float4 ev = *(const float4*)(ebc + (size_t)cb * EMB + c);
        hv.x = fmaf(hv.x, s4.x, h4.x); hv.y = fmaf(hv.y, s4.y, h4.y);
        hv.z = fmaf(hv.z, s4.z, h4.z); hv.w = fmaf(hv.w, s4.w, h4.w);
        if (dorelu) {
            hv.x = fmaxf(hv.x, 0.f); hv.y = fmaxf(hv.y, 0.f);
            hv.z = fmaxf(hv.z, 0.f); hv.w = fmaxf(hv.w, 0.f);
        }
        acc.x += fmaxf(hv.x + ev.x, 0.f);
        acc.y += fmaxf(hv.y + ev.y, 0.f);
        acc.z += fmaxf(hv.z + ev.z, 0.f);
        acc.w += fmaxf(hv.w + ev.w, 0.f);
    }
    *(float4*)(z + (size_t)n * EMB + c) = acc;
}

// ---- W1 -> fragment-linear bf16 hi/lo: w[kt 0..9][nt 0..39][lane 0..63][8] ----
__global__ void k_wconv1(const float* __restrict__ W, unsigned short* __restrict__ hi,
                         unsigned short* __restrict__ lo) {
    const int idx = blockIdx.x * 256 + threadIdx.x;
    if (idx >= 10 * 40 * 64 * 8) return;
    const int e = idx & 7;
    const int lane = (idx >> 3) & 63;
    const int nt = (idx >> 9) % 40;
    const int kt = idx / 20480;
    const int r = lane & 15, g = lane >> 4;
    const int col = nt * 16 + r;
    const int k = kt * 32 + g * 8 + e;
    const float w = (col < EMB2 && k < EMB) ? W[(size_t)k * EMB2 + col] : 0.f;
    const unsigned short h = ftobf(w);
    hi[idx] = h;
    lo[idx] = ftobf(w - u16tof(h));
}
// ---- W2 -> fragment-linear: w[kt 0..18][nt 0..19][lane][8] ----
__global__ void k_wconv2(const float* __restrict__ W, unsigned short* __restrict__ hi,
                         unsigned short* __restrict__ lo) {
    const int idx = blockIdx.x * 256 + threadIdx.x;
    if (idx >= 19 * 20 * 64 * 8) return;
    const int e = idx & 7;
    const int lane = (idx >> 3) & 63;
    const int nt = (idx >> 9) % 20;
    const int kt = idx / 10240;
    const int r = lane & 15, g = lane >> 4;
    const int col = nt * 16 + r;
    const int k = kt * 32 + g * 8 + e;
    const float w = (col < EMB && k < EMB2) ? W[(size_t)k * EMB + col] : 0.f;
    const unsigned short h = ftobf(w);
    hi[idx] = h;
    lo[idx] = ftobf(w - u16tof(h));
}

// ---- MFMA GEMM1: 32-row blocks, 512 thr; BALANCED staging (512 x float2) ----
// z1a (cols<300) -> Q in-place (barrier-protected), z1b (300-599) -> P. dbuf pipeline.
__global__ __launch_bounds__(512) void k_mfma1(
    float* __restrict__ P, float* Q,
    const unsigned short* __restrict__ whi, const unsigned short* __restrict__ wlo)
{
    __shared__ __align__(16) short AsH[2][1024];   // [buf][rg 0..1][lane][8]
    __shared__ __align__(16) short AsL[2][1024];
    const int tid = threadIdx.x;
    const int lane = tid & 63;
    const int wn = tid >> 6;                    // 0..7
    const int g = lane >> 4, r = lane & 15;
    const int row0 = blockIdx.x * 32;
    // staging: every thread 1 float2. rr = tid>>4 (0..31), oct = tid&15 (0..15)
    const int rr = tid >> 4, oct = tid & 15;
    const int srow = row0 + rr;
    const int sldo = (rr >> 4) * 512 + ((oct >> 2) * 16 + (rr & 15)) * 8 + (oct & 3) * 2;
    f32x4 acc[2][5];
#pragma unroll
    for (int rg = 0; rg < 2; ++rg)
#pragma unroll
        for (int t = 0; t < 5; ++t) acc[rg][t] = (f32x4){0.f, 0.f, 0.f, 0.f};

    // staging helpers (k multiple of 2; EMB=300 even -> no straddle)
    auto stage = [&](int kt, int b) {
        const int cc = kt * 32 + oct * 2;
        float2 v = {0.f, 0.f};
        if (cc + 1 < EMB) v = *(const float2*)(Q + (size_t)srow * EMB + cc);
        bf16x2 h2, l2;
        {
            const unsigned short hx = ftobf(v.x);
            h2[0] = (short)hx; l2[0] = (short)ftobf(v.x - u16tof(hx));
            const unsigned short hy = ftobf(v.y);
            h2[1] = (short)hy; l2[1] = (short)ftobf(v.y - u16tof(hy));
        }
        *(bf16x2*)(&AsH[b][sldo]) = h2;
        *(bf16x2*)(&AsL[b][sldo]) = l2;
    };

    stage(0, 0);
    __syncthreads();

    for (int kt = 0; kt < 10; ++kt) {
        const int cur = kt & 1;
        // prefetch next A slice (regs)
        float2 v = {0.f, 0.f};
        const bool have = (kt + 1 < 10);
        if (have) {
            const int cc = (kt + 1) * 32 + oct * 2;
            if (cc + 1 < EMB) v = *(const float2*)(Q + (size_t)srow * EMB + cc);
        }
        // consume buf[cur]
        bf16x8 ah[2], al[2];
#pragma unroll
        for (int rg = 0; rg < 2; ++rg) {
            ah[rg] = *(const bf16x8*)(&AsH[cur][rg * 512 + lane * 8]);
            al[rg] = *(const bf16x8*)(&AsL[cur][rg * 512 + lane * 8]);
        }
#pragma unroll
        for (int t = 0; t < 5; ++t) {
            const size_t wb = ((size_t)(kt * 40 + wn + t * 8) * 64 + lane) * 8;
            const bf16x8 bh = *(const bf16x8*)(whi + wb);
            const bf16x8 bl = *(const bf16x8*)(wlo + wb);
#pragma unroll
            for (int rg = 0; rg < 2; ++rg) {
                acc[rg][t] = mfma16(al[rg], bh, acc[rg][t]);
                acc[rg][t] = mfma16(ah[rg], bl, acc[rg][t]);
                acc[rg][t] = mfma16(ah[rg], bh, acc[rg][t]);
            }
        }
        // split + write buf[cur^1]
        if (have) {
            bf16x2 h2, l2;
            const unsigned short hx = ftobf(v.x);
            h2[0] = (short)hx; l2[0] = (short)ftobf(v.x - u16tof(hx));
            const unsigned short hy = ftobf(v.y);
            h2[1] = (short)hy; l2[1] = (short)ftobf(v.y - u16tof(hy));
            *(bf16x2*)(&AsH[cur ^ 1][sldo]) = h2;
            *(bf16x2*)(&AsL[cur ^ 1][sldo]) = l2;
        }
        __syncthreads();
    }
    // epilogue: all Q reads complete (barrier above)
#pragma unroll
    for (int t = 0; t < 5; ++t) {
        const int col = (wn + t * 8) * 16 + r;
#pragma unroll
        for (int rg = 0; rg < 2; ++rg) {
            const int orow = row0 + rg * 16 + g * 4;
#pragma unroll
            for (int j = 0; j < 4; ++j) {
                const float val = acc[rg][t][j];
                if (col < EMB)       Q[(size_t)(orow + j) * EMB + col] = val;          // z1a -> Q
                else if (col < EMB2) P[(size_t)(orow + j) * EMB + (col - EMB)] = val;  // z1b -> P
            }
        }
    }
}

// ---- MFMA GEMM2: 32-row blocks, 256 thr; BALANCED staging (256 x float4) ----
__global__ __launch_bounds__(256) void k_mfma2(
    float* P, const float* __restrict__ Qa,
    const float* __restrict__ sc, const float* __restrict__ sh,
    const unsigned short* __restrict__ whi, const unsigned short* __restrict__ wlo)
{
    __shared__ __align__(16) short AsH[2][1024];
    __shared__ __align__(16) short AsL[2][1024];
    const int tid = threadIdx.x;
    const int lane = tid & 63;
    const int wn = tid >> 6;                    // 0..3
    const int g = lane >> 4, r = lane & 15;
    const int row0 = blockIdx.x * 32;
    // staging: every thread 1 float4. rr = tid>>3 (0..31), quad = tid&7 (0..7)
    const int rr = tid >> 3, quad = tid & 7;
    const int srow = row0 + rr;
    const int sldo = (rr >> 4) * 512 + ((quad >> 1) * 16 + (rr & 15)) * 8 + (quad & 1) * 4;
    f32x4 acc[2][5];
#pragma unroll
    for (int rg = 0; rg < 2; ++rg)
#pragma unroll
        for (int t = 0; t < 5; ++t) acc[rg][t] = (f32x4){0.f, 0.f, 0.f, 0.f};

    // load raw A float4 for slice kt (no straddle: 300 % 4 == 0)
    auto loadA = [&](int kt, float4& v) {
        const int cc = kt * 32 + quad * 4;
        v = (float4){0.f, 0.f, 0.f, 0.f};
        if (cc + 3 < EMB)       v = *(const float4*)(Qa + (size_t)srow * EMB + cc);
        else if (cc + 3 < EMB2) v = *(const float4*)(P + (size_t)srow * EMB + (cc - EMB));
    };
    // BN1+relu+split+write
    auto writeA = [&](int kt, int b, float4 v) {
        const int cc = kt * 32 + quad * 4;
        if (cc + 3 < EMB2) {
            const float4 s4 = *(const float4*)(sc + cc);
            const float4 h4 = *(const float4*)(sh + cc);
            v.x = fmaxf(fmaf(v.x, s4.x, h4.x), 0.f);
            v.y = fmaxf(fmaf(v.y, s4.y, h4.y), 0.f);
            v.z = fmaxf(fmaf(v.z, s4.z, h4.z), 0.f);
            v.w = fmaxf(fmaf(v.w, s4.w, h4.w), 0.f);
        } else {
            v = (float4){0.f, 0.f, 0.f, 0.f};
        }
        bf16x4 h4v, l4v;
        const float vv[4] = {v.x, v.y, v.z, v.w};
#pragma unroll
        for (int e = 0; e < 4; ++e) {
            const unsigned short hh = ftobf(vv[e]);
            h4v[e] = (short)hh;
            l4v[e] = (short)ftobf(vv[e] - u16tof(hh));
        }
        *(bf16x4*)(&AsH[b][sldo]) = h4v;
        *(bf16x4*)(&AsL[b][sldo]) = l4v;
    };

    {
        float4 v;
        loadA(0, v);
        writeA(0, 0, v);
    }
    __syncthreads();

    for (int kt = 0; kt < 19; ++kt) {
        const int cur = kt & 1;
        float4 v;
        const bool have = (kt + 1 < 19);
        if (have) loadA(kt + 1, v);
        bf16x8 ah[2], al[2];
#pragma unroll
        for (int rg = 0; rg < 2; ++rg) {
            ah[rg] = *(const bf16x8*)(&AsH[cur][rg * 512 + lane * 8]);
            al[rg] = *(const bf16x8*)(&AsL[cur][rg * 512 + lane * 8]);
        }
#pragma unroll
        for (int t = 0; t < 5; ++t) {
            const size_t wb = ((size_t)(kt * 20 + wn + t * 4) * 64 + lane) * 8;
            const bf16x8 bh = *(const bf16x8*)(whi + wb);
            const bf16x8 bl = *(const bf16x8*)(wlo + wb);
#pragma unroll
            for (int rg = 0; rg < 2; ++rg) {
                acc[rg][t] = mfma16(al[rg], bh, acc[rg][t]);
                acc[rg][t] = mfma16(ah[rg], bl, acc[rg][t]);
                acc[rg][t] = mfma16(ah[rg], bh, acc[rg][t]);
            }
        }
        if (have) writeA(kt + 1, cur ^ 1, v);
        __syncthreads();
    }
#pragma unroll
    for (int t = 0; t < 5; ++t) {
        const int col = (wn + t * 4) * 16 + r;
        if (col < EMB) {
#pragma unroll
            for (int rg = 0; rg < 2; ++rg) {
                const int orow = row0 + rg * 16 + g * 4;
#pragma unroll
                for (int j = 0; j < 4; ++j)
                    P[(size_t)(orow + j) * EMB + col] = acc[rg][t][j];
            }
        }
    }
}

__global__ void k_stats(const float* __restrict__ m, float* __restrict__ sum, float* __restrict__ ss) {
    const int c = blockIdx.x * 256 + threadIdx.x;
    if (c >= EMB) return;
    const int r0 = blockIdx.y * 200;
    const int r1 = r0 + 200;
    float s = 0.f, q = 0.f;
    for (int r = r0; r < r1; ++r) {
        const float v = m[(size_t)r * EMB + c];
        s += v; q += v * v;
    }
    atomicAdd(&sum[c], s);
    atomicAdd(&ss[c], q);
}

__global__ void k_scale(const float* __restrict__ sum, const float* __restrict__ ss,
                        const float* __restrict__ g, const float* __restrict__ b,
                        float* __restrict__ scale, float* __restrict__ shift, int C) {
    const int c = blockIdx.x * 256 + threadIdx.x;
    if (c >= C) return;
    const float invN = 1.0f / (float)NN;
    const float mean = sum[c] * invN;
    const float var = ss[c] * invN - mean * mean;
    const float s = g[c] * rsqrtf(var + BN_EPS);
    scale[c] = s;
    shift[c] = b[c] - mean * s;
}

// ---- pooling with fused BN2 (no relu, last layer) ----
__global__ void k_poolg(const void* __restrict__ batch, const float* __restrict__ h,
                        float* __restrict__ out, const int* __restrict__ flag,
                        const float* __restrict__ sc, const float* __restrict__ sh) {
    __shared__ float red[4][EMB];
    const int g = blockIdx.x;
    const int f64 = *flag;
    int lo = 0, hi = NN;
    while (lo < hi) { int mid = (lo + hi) >> 1; if (geti(batch, f64, mid) < g) lo = mid + 1; else hi = mid; }
    const int s = lo;
    hi = NN;
    while (lo < hi) { int mid = (lo + hi) >> 1; if (geti(batch, f64, mid) < g + 1) lo = mid + 1; else hi = mid; }
    const int e = lo;
    const int tx = threadIdx.x, ty = threadIdx.y;
    if (tx < 75) {
        const int c = tx * 4;
        const float4 s4 = *(const float4*)(sc + c);
        const float4 h4 = *(const float4*)(sh + c);
        float4 acc; acc.x = acc.y = acc.z = acc.w = 0.f;
        int cntr = 0;
        for (int r = s + ty; r < e; r += 4) {
            const float4 v = *(const float4*)(h + (size_t)r * EMB + c);
            acc.x += v.x; acc.y += v.y; acc.z += v.z; acc.w += v.w;
            cntr++;
        }
        acc.x = fmaf(acc.x, s4.x, cntr * h4.x);
        acc.y = fmaf(acc.y, s4.y, cntr * h4.y);
        acc.z = fmaf(acc.z, s4.z, cntr * h4.z);
        acc.w = fmaf(acc.w, s4.w, cntr * h4.w);
        *(float4*)(&red[ty][c]) = acc;
    }
    __syncthreads();
    if (ty == 0 && tx < 75) {
        const int c = tx * 4;
        float4 o;
        o.x = red[0][c + 0] + red[1][c + 0] + red[2][c + 0] + red[3][c + 0];
        o.y = red[0][c + 1] + red[1][c + 1] + red[2][c + 1] + red[3][c + 1];
        o.z = red[0][c + 2] + red[1][c + 2] + red[2][c + 2] + red[3][c + 2];
        o.w = red[0][c + 3] + red[1][c + 3] + red[2][c + 3] + red[3][c + 3];
        *(float4*)(out + (size_t)g * EMB + c) = o;
    }
}

extern "C" void kernel_launch(void* const* d_in, const int* in_sizes, int n_in,
                              void* d_out, int out_size, void* d_ws, size_t ws_size,
                              hipStream_t stream) {
    const void* x     = d_in[0];
    const void* ei    = d_in[1];
    const void* eattr = d_in[2];
    const void* batch = d_in[3];
    const float* aemb = (const float*)d_in[4];
    const float* bemb = (const float*)d_in[5];
    const float* W1   = (const float*)d_in[6];
    const float* g1   = (const float*)d_in[8];
    const float* bt1  = (const float*)d_in[9];
    const float* W2   = (const float*)d_in[10];
    const float* g2   = (const float*)d_in[12];
    const float* bt2  = (const float*)d_in[13];

    char* ws = (char*)d_ws;
    float* P  = (float*)(ws);
    float* Q  = (float*)(ws + BUF_BYTES);
    char*  aux = ws + 2 * BUF_BYTES;
    float* st = (float*)(aux);
    float* sum1 = st;         float* ss1 = st + 600;
    float* sum2 = st + 1200;  float* ss2 = st + 1500;
    float* sc1  = st + 1800;  float* sh1 = st + 2400;
    float* sc2  = st + 3000;  float* sh2 = st + 3300;
    int* flag     = (int*)(aux + 16384);
    int* deg      = (int*)(aux + 16384 + 64);
    int* rowstart = (int*)(aux + 16384 + 64 + 400064);
    int* cursor   = (int*)(aux + 16384 + 64 + 800128);
    int* elist    = (int*)(aux + 16384 + 64 + 1200192);
    float* ebc    = (float*)(aux + 16384 + 64 + 2800192);
    unsigned short* wt1hi = (unsigned short*)(aux + 2888640);
    unsigned short* wt1lo = (unsigned short*)(aux + 2888640 + 409600);
    unsigned short* wt2hi = (unsigned short*)(aux + 2888640 + 819200);
    unsigned short* wt2lo = (unsigned short*)(aux + 2888640 + 819200 + 389120);

    const dim3 blk80x4(80, 4);

    k_detect<<<1, 256, 0, stream>>>((const int*)ei, flag);
    k_init<<<2, 256, 0, stream>>>(sc2, sh2);

    (void)hipMemsetAsync(deg, 0, NN * sizeof(int), stream);
    k_deg<<<(EE + 255) / 256, 256, 0, stream>>>(ei, deg, flag);
    k_scan<<<1, 1024, 0, stream>>>(deg, rowstart, cursor);
    k_scatter<<<(EE + 255) / 256, 256, 0, stream>>>(ei, eattr, cursor, elist, flag);
    k_ebc<<<60, 80, 0, stream>>>(bemb, ebc);

    k_encode<<<NN / 4, blk80x4, 0, stream>>>(x, aemb, P, flag);

    for (int i = 0; i < LL; ++i) {
        const float* W1i = W1 + (size_t)i * EMB * EMB2;
        const float* W2i = W2 + (size_t)i * EMB2 * EMB;

        (void)hipMemsetAsync(st, 0, 1800 * sizeof(float), stream);
        k_wconv1<<<(204800 + 255) / 256, 256, 0, stream>>>(W1i, wt1hi, wt1lo);
        k_wconv2<<<(194560 + 255) / 256, 256, 0, stream>>>(W2i, wt2hi, wt2lo);

        // z (in Q) = h' + sum relu(h'+e)  — 4 nodes/block (R17 form)
        k_gather<<<NN / 4, blk80x4, 0, stream>>>(rowstart, elist, ebc, P, Q,
                                                 sc2, sh2, (i > 0) ? 1 : 0);

        // z1 = z @ W1 (32-row blocks): z1a -> Q in-place, z1b -> P
        k_mfma1<<<NN / 32, 512, 0, stream>>>(P, Q, wt1hi, wt1lo);

        k_stats<<<dim3(2, 500), 256, 0, stream>>>(Q, sum1, ss1);
        k_stats<<<dim3(2, 500), 256, 0, stream>>>(P, sum1 + EMB, ss1 + EMB);
        k_scale<<<3, 256, 0, stream>>>(sum1, ss1, g1 + (size_t)i * EMB2, bt1 + (size_t)i * EMB2,
                                       sc1, sh1, EMB2);

        // h_pre = relu(BN1([Q|P])) @ W2 -> P in-place (32-row blocks)
        k_mfma2<<<NN / 32, 256, 0, stream>>>(P, Q, sc1, sh1, wt2hi, wt2lo);

        k_stats<<<dim3(2, 500), 256, 0, stream>>>(P, sum2, ss2);
        k_scale<<<2, 256, 0, stream>>>(sum2, ss2, g2 + (size_t)i * EMB, bt2 + (size_t)i * EMB,
                                       sc2, sh2, EMB);
    }

    k_poolg<<<GG, blk80x4, 0, stream>>>(batch, P, (float*)d_out, flag, sc2, sh2);
}